// Round 14
// baseline (204.625 us; speedup 1.0000x reference)
//
#include <hip/hip_runtime.h>
#include <hip/hip_fp16.h>

// GCN: N=50000 nodes, E=800000 edges, 64 -> 96 -> 96 -> 32, fp32.
// R14: (a) revert R11's sgemm1 MS=24 and 8-deep gather unroll (net +7us) to
// R10-proven forms (MS=32, 4-deep); keep R11's pass1 grid fix (196x256).
// (b) NEW: sgemm2+FC fused via LDS. Block = 64 nodes x 4 slices (MS=24,
// same parallelism as split sgemm2 - avoids R9's 1-thread/node cliff).
// Phase1: h2 slice -> LDS [64][101] (pad 101: banks 5*lane mod 32, <=2-way).
// Phase2: wave-per-M-slice (m0=(t>>6)*8) -> Wfc/bfc wave-uniform -> s_load.
// Kills the 38.4MB h2 global roundtrip + one dispatch.
// Pipeline:
//   pass1: bucket edges by dst/98; pass2: CSR + dinv + perm + u_h=fp16(di*x)
//   B1 = gather64(u_h,perm);  g1_h = fp16(di*relu(di*(B1@W1)+b1))
//   B2 = gather96(g1_h,perm); out = relu(di*(B2@W2)+b2) @ Wfc + bfc [fused]

constexpr int NN = 50000;
constexpr int NE = 800000;
constexpr int NB = 512;     // buckets
constexpr int NPB = 98;     // nodes per bucket (512*98 = 50176 >= NN)
constexpr int BCAP = 2048;  // max edges per bucket (mean 1563; verified fit)
constexpr int EPB = 4096;   // edges per pass1 block
constexpr int P1B = 256;    // pass1 block size
constexpr int NP1 = (NE + EPB - 1) / EPB;  // 196 blocks

__global__ void zero_bcnt(int* bcnt) {
  int i = threadIdx.x;
  if (i < NB) bcnt[i] = 0;
}

// ---------------- CSR pass 1: block-local sort + bulk reservation ----------
__global__ __launch_bounds__(P1B) void csr_pass1(const int* __restrict__ ei,
                                                 int* __restrict__ bcnt,
                                                 unsigned* __restrict__ bbuf) {
  __shared__ unsigned sorted[EPB];  // 16KB
  __shared__ int hist[NB];
  __shared__ int lofs[NB];   // local exclusive prefix
  __shared__ int cursor[NB];
  __shared__ int gbase[NB];  // global reserved base within bucket
  __shared__ int psum[P1B];
  const int t = threadIdx.x;
  const int e0 = blockIdx.x * EPB;
  const int ecnt = min(EPB, NE - e0);

  for (int i = t; i < NB; i += P1B) hist[i] = 0;
  __syncthreads();

  // phase A: histogram (16 edges/thread)
  for (int i = t; i < ecnt; i += P1B) {
    unsigned dst = (unsigned)ei[NE + e0 + i];
    atomicAdd(&hist[dst / NPB], 1);
  }
  __syncthreads();

  // phase B: pair-scan 512 buckets with 256 threads + bulk reservation
  const int h0 = hist[2 * t], h1 = hist[2 * t + 1];
  psum[t] = h0 + h1;
  __syncthreads();
  for (int off = 1; off < P1B; off <<= 1) {
    int v = 0;
    if (t >= off) v = psum[t - off];
    __syncthreads();
    psum[t] += v;
    __syncthreads();
  }
  {
    const int pex = psum[t] - (h0 + h1);  // exclusive pair base
    lofs[2 * t] = pex;
    lofs[2 * t + 1] = pex + h0;
    cursor[2 * t] = pex;
    cursor[2 * t + 1] = pex + h0;
    gbase[2 * t] = atomicAdd(&bcnt[2 * t], h0);
    gbase[2 * t + 1] = atomicAdd(&bcnt[2 * t + 1], h1);
  }
  __syncthreads();

  // phase C: LDS scatter sorted by bucket
  for (int i = t; i < ecnt; i += P1B) {
    unsigned src = (unsigned)ei[e0 + i];
    unsigned dst = (unsigned)ei[NE + e0 + i];
    unsigned b = dst / NPB;
    unsigned dl = dst - b * NPB;
    int pos = atomicAdd(&cursor[b], 1);
    sorted[pos] = (b << 23) | (dl << 16) | src;
  }
  __syncthreads();

  // phase D: run-coalesced global writes
  for (int i = t; i < ecnt; i += P1B) {
    unsigned pw = sorted[i];
    unsigned b = pw >> 23;
    int off_in_b = gbase[b] + (i - lofs[b]);
    if (off_in_b < BCAP)
      bbuf[b * BCAP + off_in_b] = pw & 0x007FFFFFu;  // (dl<<16)|src
  }
}

// ------- CSR pass 2: per-bucket LDS sort + CSR + degree-sorted perm -------
__global__ __launch_bounds__(256) void csr_pass2(
    const int* __restrict__ bcnt, const unsigned* __restrict__ bbuf,
    const float* __restrict__ x, int* __restrict__ row_start,
    int* __restrict__ counts, float* __restrict__ dinv,
    __half* __restrict__ u, unsigned short* __restrict__ srcs,
    unsigned* __restrict__ perm) {
  __shared__ int s_red[256];
  __shared__ int s_cnt[128];
  __shared__ int s_scan[128];
  __shared__ int s_cur[128];
  __shared__ float s_dinv[128];
  __shared__ unsigned short s_sorted[BCAP];
  __shared__ int d_hist[64];
  __shared__ int d_cur[64];
  __shared__ int s_permL[NPB];
  const int b = blockIdx.x, t = threadIdx.x;
  const int cnt_b = min(bcnt[b], BCAP);

  int acc = 0;
  for (int j = t; j < b; j += 256) acc += min(bcnt[j], BCAP);
  s_red[t] = acc;
  __syncthreads();
  for (int off = 128; off > 0; off >>= 1) {
    if (t < off) s_red[t] += s_red[t + off];
    __syncthreads();
  }
  const int base = s_red[0];

  if (t < 128) s_cnt[t] = 0;
  __syncthreads();
  for (int i = t; i < cnt_b; i += 256)
    atomicAdd(&s_cnt[bbuf[b * BCAP + i] >> 16], 1);
  __syncthreads();

  if (t < 128) s_scan[t] = s_cnt[t];
  __syncthreads();
  for (int off = 1; off < 128; off <<= 1) {
    int v = 0;
    if (t < 128 && t >= off) v = s_scan[t - off];
    __syncthreads();
    if (t < 128) s_scan[t] += v;
    __syncthreads();
  }
  if (t < 128) s_cur[t] = s_scan[t] - s_cnt[t];  // exclusive

  const int node = b * NPB + t;
  if (t < NPB && node < NN) {
    int c = s_cnt[t];
    row_start[node] = base + s_scan[t] - c;
    counts[node] = c;
    float di = rsqrtf(1.0f + (float)c);
    dinv[node] = di;
    s_dinv[t] = di;
  }
  __syncthreads();

  for (int i = t; i < cnt_b; i += 256) {
    unsigned w = bbuf[b * BCAP + i];
    int pos = atomicAdd(&s_cur[w >> 16], 1);
    s_sorted[pos] = (unsigned short)(w & 0xFFFFu);
  }
  __syncthreads();
  for (int i = t; i < cnt_b; i += 256) srcs[base + i] = s_sorted[i];

  // ---- degree-sorted perm for this bucket (s_cnt intact) ----
  const int na = max(0, min(NN - b * NPB, NPB));  // active nodes in bucket
  if (t < 64) d_hist[t] = 0;
  __syncthreads();
  const bool activeN = (t < na);
  const int deg = activeN ? min(s_cnt[t], 63) : 0;
  if (activeN) atomicAdd(&d_hist[deg], 1);
  __syncthreads();
  if (t < 64) d_cur[t] = d_hist[t];
  __syncthreads();
  for (int off = 1; off < 64; off <<= 1) {
    int v = 0;
    if (t < 64 && t >= off) v = d_cur[t - off];
    __syncthreads();
    if (t < 64) d_cur[t] += v;
    __syncthreads();
  }
  if (t < 64) d_cur[t] -= d_hist[t];  // exclusive
  __syncthreads();
  if (activeN) {
    int r = atomicAdd(&d_cur[deg], 1);
    s_permL[r] = t;
  }
  __syncthreads();
  if (t < NPB)
    perm[b * NPB + t] =
        (t < na) ? (unsigned)(b * NPB + s_permL[t]) : 0xFFFFFFFFu;

  // fused: u = fp16(dinv * x), stride 64 halves
  const float4* x4 = (const float4*)x;
  for (int i = t; i < NPB * 16; i += 256) {
    int nl = i >> 4, q = i & 15;
    int n = b * NPB + nl;
    if (n < NN) {
      float di = s_dinv[nl];
      float4 v = x4[(size_t)n * 16 + q];
      __half2 h01 = __floats2half2_rn(v.x * di, v.y * di);
      __half2 h23 = __floats2half2_rn(v.z * di, v.w * di);
      uint2 pk;
      pk.x = *(unsigned*)&h01;
      pk.y = *(unsigned*)&h23;
      *(uint2*)(u + (size_t)n * 64 + 4 * q) = pk;
    }
  }
}

// ------- perm-ordered gather: B[n] = A[n] + sum_{s in adj(n)} A[s] -------
// A fp16 full rows (16B/lane contiguous, line-friendly); B fp32 sequential.
// Degree-sorted perm order -> uniform loop length per wave. 4-deep MLP (R10).
template <int C>
__global__ __launch_bounds__(256) void gather_h(
    const unsigned* __restrict__ perm, const int* __restrict__ row_start,
    const int* __restrict__ counts, const unsigned short* __restrict__ srcs,
    const __half* __restrict__ A, float* __restrict__ B) {
  constexpr int QP = C / 8;  // 16B chunks per row: 12 (96ch) or 8 (64ch)
  int gid = blockIdx.x * blockDim.x + threadIdx.x;
  if (gid >= NB * NPB * QP) return;
  int i, q;
  if constexpr ((QP & (QP - 1)) == 0) {
    i = gid >> 3;  // QP == 8
    q = gid & 7;
  } else {
    i = gid / QP;
    q = gid - i * QP;
  }
  const unsigned node = perm[i];
  if (node == 0xFFFFFFFFu) return;
  const int n = (int)node;
  const uint4* A4 = (const uint4*)A + q;  // row = QP uint4 (8 halves each)

  float a[8] = {};
  {  // self-loop term
    uint4 v = A4[(size_t)n * QP];
    const __half2* h = (const __half2*)&v;
    #pragma unroll
    for (int k = 0; k < 4; ++k) {
      float2 f = __half22float2(h[k]);
      a[2 * k] = f.x;
      a[2 * k + 1] = f.y;
    }
  }
  const int s0 = row_start[n];
  const int cnt = counts[n];
  int p = 0;
  for (; p + 4 <= cnt; p += 4) {  // 4 independent loads in flight
    int sa = srcs[s0 + p + 0];
    int sb = srcs[s0 + p + 1];
    int sc = srcs[s0 + p + 2];
    int sd = srcs[s0 + p + 3];
    uint4 va = A4[(size_t)sa * QP];
    uint4 vb = A4[(size_t)sb * QP];
    uint4 vc = A4[(size_t)sc * QP];
    uint4 vd = A4[(size_t)sd * QP];
    const __half2* ha = (const __half2*)&va;
    const __half2* hb = (const __half2*)&vb;
    const __half2* hc = (const __half2*)&vc;
    const __half2* hd = (const __half2*)&vd;
    #pragma unroll
    for (int k = 0; k < 4; ++k) {
      float2 fa = __half22float2(ha[k]);
      float2 fb = __half22float2(hb[k]);
      float2 fc = __half22float2(hc[k]);
      float2 fd = __half22float2(hd[k]);
      a[2 * k] += (fa.x + fb.x) + (fc.x + fd.x);
      a[2 * k + 1] += (fa.y + fb.y) + (fc.y + fd.y);
    }
  }
  for (; p < cnt; ++p) {
    int s = srcs[s0 + p];
    uint4 v = A4[(size_t)s * QP];
    const __half2* h = (const __half2*)&v;
    #pragma unroll
    for (int k = 0; k < 4; ++k) {
      float2 f = __half22float2(h[k]);
      a[2 * k] += f.x;
      a[2 * k + 1] += f.y;
    }
  }
  float* bp = B + (size_t)n * C + 8 * q;
  *(float4*)bp = make_float4(a[0], a[1], a[2], a[3]);
  *(float4*)(bp + 4) = make_float4(a[4], a[5], a[6], a[7]);
}

// ---------------- SGPR-W row GEMM (layer 1) ----------------
// thread = (node, M-slice of MS). acc in VGPRs; W via wave-uniform s_load.
// EMODE 1: di*relu(di*acc+b).  OH: fp16 out.
template <int K, int M, int MS, int EMODE, int OH>
__global__ __launch_bounds__(256) void sgemm(
    const float* __restrict__ X, const float* __restrict__ W,
    const float* __restrict__ bias, const float* __restrict__ dinv,
    void* __restrict__ outv) {
  constexpr int NS = M / MS;
  constexpr int WQ = MS / 4;
  const int bid = blockIdx.x;
  const int chunk = (NS == 1) ? bid : bid / NS;
  const int slice = (NS == 1) ? 0 : bid - chunk * NS;
  const int c0 = slice * MS;
  const int t = threadIdx.x;
  const int nr = chunk * 256 + t;
  const bool act = nr < NN;
  const int n = act ? nr : NN - 1;  // clamp: safe loads, store guarded

  float acc[MS] = {};
  const float4* __restrict__ xr = (const float4*)(X + (size_t)n * K);
  #pragma unroll 4
  for (int kq = 0; kq < K / 4; ++kq) {
    float4 xv = xr[kq];
    const float xk[4] = {xv.x, xv.y, xv.z, xv.w};
    #pragma unroll
    for (int c = 0; c < 4; ++c) {
      const float* __restrict__ wrow = W + (size_t)(4 * kq + c) * M + c0;
      #pragma unroll
      for (int j = 0; j < MS; ++j)  // wrow[j] is wave-uniform -> s_load
        acc[j] = fmaf(xk[c], wrow[j], acc[j]);
    }
  }

  if (act) {
    const float di = (EMODE != 3) ? dinv[n] : 0.f;
    #pragma unroll
    for (int j4 = 0; j4 < WQ; ++j4) {
      float b0 = bias[c0 + 4 * j4 + 0], b1 = bias[c0 + 4 * j4 + 1];
      float b2 = bias[c0 + 4 * j4 + 2], b3 = bias[c0 + 4 * j4 + 3];
      float a0 = acc[4 * j4 + 0], a1 = acc[4 * j4 + 1];
      float a2 = acc[4 * j4 + 2], a3 = acc[4 * j4 + 3];
      float4 r;
      if (EMODE == 1) {
        r.x = di * fmaxf(fmaf(di, a0, b0), 0.f);
        r.y = di * fmaxf(fmaf(di, a1, b1), 0.f);
        r.z = di * fmaxf(fmaf(di, a2, b2), 0.f);
        r.w = di * fmaxf(fmaf(di, a3, b3), 0.f);
      } else if (EMODE == 2) {
        r.x = fmaxf(fmaf(di, a0, b0), 0.f);
        r.y = fmaxf(fmaf(di, a1, b1), 0.f);
        r.z = fmaxf(fmaf(di, a2, b2), 0.f);
        r.w = fmaxf(fmaf(di, a3, b3), 0.f);
      } else {
        r.x = a0 + b0; r.y = a1 + b1; r.z = a2 + b2; r.w = a3 + b3;
      }
      if (OH) {
        __half2 h01 = __floats2half2_rn(r.x, r.y);
        __half2 h23 = __floats2half2_rn(r.z, r.w);
        uint2 pk;
        pk.x = *(unsigned*)&h01;
        pk.y = *(unsigned*)&h23;
        *(uint2*)((__half*)outv + (size_t)n * M + c0 + 4 * j4) = pk;
      } else {
        *(float4*)((float*)outv + (size_t)n * M + c0 + 4 * j4) = r;
      }
    }
  }
}

// ---------- fused layer-2 GEMM + FC via LDS staging ----------
// Block = 256 thr = 64 nodes x 4 slices (MS=24 - same shape as split sgemm2).
// Phase 1: acc[24] = X[n] @ W2[:,c0:c0+24] (W2 s_load); h2 slice -> LDS,
//          row stride 101 (5 mod 32 -> <=2-way banks, free).
// Phase 2: wave w handles m-slice m0=w*8 for all 64 nodes (lane=node):
//          Wfc/bfc wave-uniform -> s_load; sh2 scalar reads conflict-free.
__global__ __launch_bounds__(256) void sgemm2fc(
    const float* __restrict__ X, const float* __restrict__ W2,
    const float* __restrict__ b2, const float* __restrict__ Wfc,
    const float* __restrict__ bfc, const float* __restrict__ dinv,
    float* __restrict__ out) {
  __shared__ float sh2[64 * 101];  // 25.9 KB
  const int t = threadIdx.x;
  const int nl = t >> 2;
  const int c0 = (t & 3) * 24;
  const int nr = blockIdx.x * 64 + nl;
  const bool act = nr < NN;
  const int n = act ? nr : NN - 1;

  float acc[24] = {};
  const float4* __restrict__ xr = (const float4*)(X + (size_t)n * 96);
  #pragma unroll 4
  for (int kq = 0; kq < 24; ++kq) {
    float4 xv = xr[kq];
    const float xk[4] = {xv.x, xv.y, xv.z, xv.w};
    #pragma unroll
    for (int c = 0; c < 4; ++c) {
      const float* __restrict__ wrow = W2 + (size_t)(4 * kq + c) * 96 + c0;
      #pragma unroll
      for (int j = 0; j < 24; ++j)  // wave-uniform -> s_load
        acc[j] = fmaf(xk[c], wrow[j], acc[j]);
    }
  }
  {
    const float di = dinv[n];
    float* sp = sh2 + nl * 101 + c0;
    #pragma unroll
    for (int j = 0; j < 24; ++j)
      sp[j] = fmaxf(fmaf(di, acc[j], b2[c0 + j]), 0.f);
  }
  __syncthreads();

  // phase 2: lane = node, wave = m-slice
  const int nl2 = t & 63;
  const int m0 = (t >> 6) * 8;
  const int nr2 = blockIdx.x * 64 + nl2;
  float o[8] = {};
  const float* __restrict__ hrow = sh2 + nl2 * 101;
  #pragma unroll 8
  for (int k = 0; k < 96; ++k) {
    const float hk = hrow[k];
    const float* __restrict__ wr = Wfc + (size_t)k * 32 + m0;  // uniform
    #pragma unroll
    for (int j = 0; j < 8; ++j) o[j] = fmaf(hk, wr[j], o[j]);
  }
  if (nr2 < NN) {
    float* op = out + (size_t)nr2 * 32 + m0;
    float4 r0, r1;
    r0.x = o[0] + bfc[m0 + 0]; r0.y = o[1] + bfc[m0 + 1];
    r0.z = o[2] + bfc[m0 + 2]; r0.w = o[3] + bfc[m0 + 3];
    r1.x = o[4] + bfc[m0 + 4]; r1.y = o[5] + bfc[m0 + 5];
    r1.z = o[6] + bfc[m0 + 6]; r1.w = o[7] + bfc[m0 + 7];
    *(float4*)op = r0;
    *(float4*)(op + 4) = r1;
  }
}

extern "C" void kernel_launch(void* const* d_in, const int* in_sizes, int n_in,
                              void* d_out, int out_size, void* d_ws,
                              size_t ws_size, hipStream_t stream) {
  const float* x   = (const float*)d_in[0];
  const int*   ei  = (const int*)d_in[1];
  const float* W1  = (const float*)d_in[2];
  const float* b1  = (const float*)d_in[3];
  const float* W2  = (const float*)d_in[4];
  const float* b2  = (const float*)d_in[5];
  const float* Wfc = (const float*)d_in[6];
  const float* bfc = (const float*)d_in[7];
  float* out = (float*)d_out;

  // workspace: lifetime-reused regions
  //   R0 [NN*96 f32]: u_h (fp16 s64) | g1_h (fp16 s96)
  //   R1 [NN*96 f32]: bbuf | B1 (f32 s64) | B2 (f32 s96)
  float* dinv = (float*)d_ws;                        // [50048]
  float* R0 = dinv + 50048;                          // [NN*96]
  float* R1 = R0 + (size_t)NN * 96;                  // [NN*96]
  int* row_start = (int*)(R1 + (size_t)NN * 96);     // [50048]
  int* counts = row_start + 50048;                   // [50048]
  int* bcnt = counts + 50048;                        // [512]
  unsigned short* srcs = (unsigned short*)(bcnt + 512);  // [NE] u16
  unsigned* perm = (unsigned*)(srcs + NE);           // [NB*NPB]
  unsigned* bbuf = (unsigned*)R1;                    // 4MB scratch
  __half* u_h = (__half*)R0;
  __half* g1_h = (__half*)R0;
  float* B1 = R1;
  float* B2 = R1;

  zero_bcnt<<<1, 512, 0, stream>>>(bcnt);
  csr_pass1<<<NP1, P1B, 0, stream>>>(ei, bcnt, bbuf);
  csr_pass2<<<NB, 256, 0, stream>>>(bcnt, bbuf, x, row_start, counts, dinv,
                                    u_h, srcs, perm);

  constexpr int CH = (NN + 255) / 256;  // 196 node chunks

  // B1 = gather64(u_h, perm): R0 -> R1
  gather_h<64><<<(NB * NPB * 8 + 255) / 256, 256, 0, stream>>>(
      perm, row_start, counts, srcs, u_h, B1);
  // g1_h = fp16(di*relu(di*(B1@W1) + b1)): R1 -> R0  (MS=32, R10-proven)
  sgemm<64, 96, 32, 1, 1><<<CH * 3, 256, 0, stream>>>(B1, W1, b1, dinv, g1_h);
  // B2 = gather96(g1_h, perm): R0 -> R1
  gather_h<96><<<(NB * NPB * 12 + 255) / 256, 256, 0, stream>>>(
      perm, row_start, counts, srcs, g1_h, B2);
  // out = relu(di*(B2@W2)+b2) @ Wfc + bfc: fused, LDS-staged
  sgemm2fc<<<(NN + 63) / 64, 256, 0, stream>>>(B2, W2, b2, Wfc, bfc, dinv,
                                               out);
}

// Round 15
// 203.579 us; speedup vs baseline: 1.0051x; 1.0051x over previous
//
#include <hip/hip_runtime.h>
#include <hip/hip_fp16.h>

// GCN: N=50000 nodes, E=800000 edges, 64 -> 96 -> 96 -> 32, fp32.
// R15: fix R14's sgemm2fc. R14 mapped slice = (t&3) -> c0 LANE-VARYING ->
// W2 addresses not wave-uniform -> per-lane VMEM loads (~1.8GB L2 traffic,
// 106us). Fix: wave = slice (c0 = (t>>6)*24, uniform within wave -> s_load
// restored), lane = node (t&63). Phase 2 already wave-uniform. Everything
// else identical to R14.
// Pipeline:
//   pass1: bucket edges by dst/98; pass2: CSR + dinv + perm + u_h=fp16(di*x)
//   B1 = gather64(u_h,perm);  g1_h = fp16(di*relu(di*(B1@W1)+b1))
//   B2 = gather96(g1_h,perm); out = relu(di*(B2@W2)+b2) @ Wfc + bfc [fused]

constexpr int NN = 50000;
constexpr int NE = 800000;
constexpr int NB = 512;     // buckets
constexpr int NPB = 98;     // nodes per bucket (512*98 = 50176 >= NN)
constexpr int BCAP = 2048;  // max edges per bucket (mean 1563; verified fit)
constexpr int EPB = 4096;   // edges per pass1 block
constexpr int P1B = 256;    // pass1 block size
constexpr int NP1 = (NE + EPB - 1) / EPB;  // 196 blocks

__global__ void zero_bcnt(int* bcnt) {
  int i = threadIdx.x;
  if (i < NB) bcnt[i] = 0;
}

// ---------------- CSR pass 1: block-local sort + bulk reservation ----------
__global__ __launch_bounds__(P1B) void csr_pass1(const int* __restrict__ ei,
                                                 int* __restrict__ bcnt,
                                                 unsigned* __restrict__ bbuf) {
  __shared__ unsigned sorted[EPB];  // 16KB
  __shared__ int hist[NB];
  __shared__ int lofs[NB];   // local exclusive prefix
  __shared__ int cursor[NB];
  __shared__ int gbase[NB];  // global reserved base within bucket
  __shared__ int psum[P1B];
  const int t = threadIdx.x;
  const int e0 = blockIdx.x * EPB;
  const int ecnt = min(EPB, NE - e0);

  for (int i = t; i < NB; i += P1B) hist[i] = 0;
  __syncthreads();

  // phase A: histogram (16 edges/thread)
  for (int i = t; i < ecnt; i += P1B) {
    unsigned dst = (unsigned)ei[NE + e0 + i];
    atomicAdd(&hist[dst / NPB], 1);
  }
  __syncthreads();

  // phase B: pair-scan 512 buckets with 256 threads + bulk reservation
  const int h0 = hist[2 * t], h1 = hist[2 * t + 1];
  psum[t] = h0 + h1;
  __syncthreads();
  for (int off = 1; off < P1B; off <<= 1) {
    int v = 0;
    if (t >= off) v = psum[t - off];
    __syncthreads();
    psum[t] += v;
    __syncthreads();
  }
  {
    const int pex = psum[t] - (h0 + h1);  // exclusive pair base
    lofs[2 * t] = pex;
    lofs[2 * t + 1] = pex + h0;
    cursor[2 * t] = pex;
    cursor[2 * t + 1] = pex + h0;
    gbase[2 * t] = atomicAdd(&bcnt[2 * t], h0);
    gbase[2 * t + 1] = atomicAdd(&bcnt[2 * t + 1], h1);
  }
  __syncthreads();

  // phase C: LDS scatter sorted by bucket
  for (int i = t; i < ecnt; i += P1B) {
    unsigned src = (unsigned)ei[e0 + i];
    unsigned dst = (unsigned)ei[NE + e0 + i];
    unsigned b = dst / NPB;
    unsigned dl = dst - b * NPB;
    int pos = atomicAdd(&cursor[b], 1);
    sorted[pos] = (b << 23) | (dl << 16) | src;
  }
  __syncthreads();

  // phase D: run-coalesced global writes
  for (int i = t; i < ecnt; i += P1B) {
    unsigned pw = sorted[i];
    unsigned b = pw >> 23;
    int off_in_b = gbase[b] + (i - lofs[b]);
    if (off_in_b < BCAP)
      bbuf[b * BCAP + off_in_b] = pw & 0x007FFFFFu;  // (dl<<16)|src
  }
}

// ------- CSR pass 2: per-bucket LDS sort + CSR + degree-sorted perm -------
__global__ __launch_bounds__(256) void csr_pass2(
    const int* __restrict__ bcnt, const unsigned* __restrict__ bbuf,
    const float* __restrict__ x, int* __restrict__ row_start,
    int* __restrict__ counts, float* __restrict__ dinv,
    __half* __restrict__ u, unsigned short* __restrict__ srcs,
    unsigned* __restrict__ perm) {
  __shared__ int s_red[256];
  __shared__ int s_cnt[128];
  __shared__ int s_scan[128];
  __shared__ int s_cur[128];
  __shared__ float s_dinv[128];
  __shared__ unsigned short s_sorted[BCAP];
  __shared__ int d_hist[64];
  __shared__ int d_cur[64];
  __shared__ int s_permL[NPB];
  const int b = blockIdx.x, t = threadIdx.x;
  const int cnt_b = min(bcnt[b], BCAP);

  int acc = 0;
  for (int j = t; j < b; j += 256) acc += min(bcnt[j], BCAP);
  s_red[t] = acc;
  __syncthreads();
  for (int off = 128; off > 0; off >>= 1) {
    if (t < off) s_red[t] += s_red[t + off];
    __syncthreads();
  }
  const int base = s_red[0];

  if (t < 128) s_cnt[t] = 0;
  __syncthreads();
  for (int i = t; i < cnt_b; i += 256)
    atomicAdd(&s_cnt[bbuf[b * BCAP + i] >> 16], 1);
  __syncthreads();

  if (t < 128) s_scan[t] = s_cnt[t];
  __syncthreads();
  for (int off = 1; off < 128; off <<= 1) {
    int v = 0;
    if (t < 128 && t >= off) v = s_scan[t - off];
    __syncthreads();
    if (t < 128) s_scan[t] += v;
    __syncthreads();
  }
  if (t < 128) s_cur[t] = s_scan[t] - s_cnt[t];  // exclusive

  const int node = b * NPB + t;
  if (t < NPB && node < NN) {
    int c = s_cnt[t];
    row_start[node] = base + s_scan[t] - c;
    counts[node] = c;
    float di = rsqrtf(1.0f + (float)c);
    dinv[node] = di;
    s_dinv[t] = di;
  }
  __syncthreads();

  for (int i = t; i < cnt_b; i += 256) {
    unsigned w = bbuf[b * BCAP + i];
    int pos = atomicAdd(&s_cur[w >> 16], 1);
    s_sorted[pos] = (unsigned short)(w & 0xFFFFu);
  }
  __syncthreads();
  for (int i = t; i < cnt_b; i += 256) srcs[base + i] = s_sorted[i];

  // ---- degree-sorted perm for this bucket (s_cnt intact) ----
  const int na = max(0, min(NN - b * NPB, NPB));  // active nodes in bucket
  if (t < 64) d_hist[t] = 0;
  __syncthreads();
  const bool activeN = (t < na);
  const int deg = activeN ? min(s_cnt[t], 63) : 0;
  if (activeN) atomicAdd(&d_hist[deg], 1);
  __syncthreads();
  if (t < 64) d_cur[t] = d_hist[t];
  __syncthreads();
  for (int off = 1; off < 64; off <<= 1) {
    int v = 0;
    if (t < 64 && t >= off) v = d_cur[t - off];
    __syncthreads();
    if (t < 64) d_cur[t] += v;
    __syncthreads();
  }
  if (t < 64) d_cur[t] -= d_hist[t];  // exclusive
  __syncthreads();
  if (activeN) {
    int r = atomicAdd(&d_cur[deg], 1);
    s_permL[r] = t;
  }
  __syncthreads();
  if (t < NPB)
    perm[b * NPB + t] =
        (t < na) ? (unsigned)(b * NPB + s_permL[t]) : 0xFFFFFFFFu;

  // fused: u = fp16(dinv * x), stride 64 halves
  const float4* x4 = (const float4*)x;
  for (int i = t; i < NPB * 16; i += 256) {
    int nl = i >> 4, q = i & 15;
    int n = b * NPB + nl;
    if (n < NN) {
      float di = s_dinv[nl];
      float4 v = x4[(size_t)n * 16 + q];
      __half2 h01 = __floats2half2_rn(v.x * di, v.y * di);
      __half2 h23 = __floats2half2_rn(v.z * di, v.w * di);
      uint2 pk;
      pk.x = *(unsigned*)&h01;
      pk.y = *(unsigned*)&h23;
      *(uint2*)(u + (size_t)n * 64 + 4 * q) = pk;
    }
  }
}

// ------- perm-ordered gather: B[n] = A[n] + sum_{s in adj(n)} A[s] -------
// A fp16 full rows (16B/lane contiguous, line-friendly); B fp32 sequential.
// Degree-sorted perm order -> uniform loop length per wave. 4-deep MLP.
template <int C>
__global__ __launch_bounds__(256) void gather_h(
    const unsigned* __restrict__ perm, const int* __restrict__ row_start,
    const int* __restrict__ counts, const unsigned short* __restrict__ srcs,
    const __half* __restrict__ A, float* __restrict__ B) {
  constexpr int QP = C / 8;  // 16B chunks per row: 12 (96ch) or 8 (64ch)
  int gid = blockIdx.x * blockDim.x + threadIdx.x;
  if (gid >= NB * NPB * QP) return;
  int i, q;
  if constexpr ((QP & (QP - 1)) == 0) {
    i = gid >> 3;  // QP == 8
    q = gid & 7;
  } else {
    i = gid / QP;
    q = gid - i * QP;
  }
  const unsigned node = perm[i];
  if (node == 0xFFFFFFFFu) return;
  const int n = (int)node;
  const uint4* A4 = (const uint4*)A + q;  // row = QP uint4 (8 halves each)

  float a[8] = {};
  {  // self-loop term
    uint4 v = A4[(size_t)n * QP];
    const __half2* h = (const __half2*)&v;
    #pragma unroll
    for (int k = 0; k < 4; ++k) {
      float2 f = __half22float2(h[k]);
      a[2 * k] = f.x;
      a[2 * k + 1] = f.y;
    }
  }
  const int s0 = row_start[n];
  const int cnt = counts[n];
  int p = 0;
  for (; p + 4 <= cnt; p += 4) {  // 4 independent loads in flight
    int sa = srcs[s0 + p + 0];
    int sb = srcs[s0 + p + 1];
    int sc = srcs[s0 + p + 2];
    int sd = srcs[s0 + p + 3];
    uint4 va = A4[(size_t)sa * QP];
    uint4 vb = A4[(size_t)sb * QP];
    uint4 vc = A4[(size_t)sc * QP];
    uint4 vd = A4[(size_t)sd * QP];
    const __half2* ha = (const __half2*)&va;
    const __half2* hb = (const __half2*)&vb;
    const __half2* hc = (const __half2*)&vc;
    const __half2* hd = (const __half2*)&vd;
    #pragma unroll
    for (int k = 0; k < 4; ++k) {
      float2 fa = __half22float2(ha[k]);
      float2 fb = __half22float2(hb[k]);
      float2 fc = __half22float2(hc[k]);
      float2 fd = __half22float2(hd[k]);
      a[2 * k] += (fa.x + fb.x) + (fc.x + fd.x);
      a[2 * k + 1] += (fa.y + fb.y) + (fc.y + fd.y);
    }
  }
  for (; p < cnt; ++p) {
    int s = srcs[s0 + p];
    uint4 v = A4[(size_t)s * QP];
    const __half2* h = (const __half2*)&v;
    #pragma unroll
    for (int k = 0; k < 4; ++k) {
      float2 f = __half22float2(h[k]);
      a[2 * k] += f.x;
      a[2 * k + 1] += f.y;
    }
  }
  float* bp = B + (size_t)n * C + 8 * q;
  *(float4*)bp = make_float4(a[0], a[1], a[2], a[3]);
  *(float4*)(bp + 4) = make_float4(a[4], a[5], a[6], a[7]);
}

// ---------------- SGPR-W row GEMM (layer 1) ----------------
// thread = (node, M-slice of MS). acc in VGPRs; W via wave-uniform s_load.
// EMODE 1: di*relu(di*acc+b).  OH: fp16 out.
template <int K, int M, int MS, int EMODE, int OH>
__global__ __launch_bounds__(256) void sgemm(
    const float* __restrict__ X, const float* __restrict__ W,
    const float* __restrict__ bias, const float* __restrict__ dinv,
    void* __restrict__ outv) {
  constexpr int NS = M / MS;
  constexpr int WQ = MS / 4;
  const int bid = blockIdx.x;
  const int chunk = (NS == 1) ? bid : bid / NS;
  const int slice = (NS == 1) ? 0 : bid - chunk * NS;
  const int c0 = slice * MS;
  const int t = threadIdx.x;
  const int nr = chunk * 256 + t;
  const bool act = nr < NN;
  const int n = act ? nr : NN - 1;  // clamp: safe loads, store guarded

  float acc[MS] = {};
  const float4* __restrict__ xr = (const float4*)(X + (size_t)n * K);
  #pragma unroll 4
  for (int kq = 0; kq < K / 4; ++kq) {
    float4 xv = xr[kq];
    const float xk[4] = {xv.x, xv.y, xv.z, xv.w};
    #pragma unroll
    for (int c = 0; c < 4; ++c) {
      const float* __restrict__ wrow = W + (size_t)(4 * kq + c) * M + c0;
      #pragma unroll
      for (int j = 0; j < MS; ++j)  // wrow[j] is wave-uniform -> s_load
        acc[j] = fmaf(xk[c], wrow[j], acc[j]);
    }
  }

  if (act) {
    const float di = (EMODE != 3) ? dinv[n] : 0.f;
    #pragma unroll
    for (int j4 = 0; j4 < WQ; ++j4) {
      float b0 = bias[c0 + 4 * j4 + 0], b1 = bias[c0 + 4 * j4 + 1];
      float b2 = bias[c0 + 4 * j4 + 2], b3 = bias[c0 + 4 * j4 + 3];
      float a0 = acc[4 * j4 + 0], a1 = acc[4 * j4 + 1];
      float a2 = acc[4 * j4 + 2], a3 = acc[4 * j4 + 3];
      float4 r;
      if (EMODE == 1) {
        r.x = di * fmaxf(fmaf(di, a0, b0), 0.f);
        r.y = di * fmaxf(fmaf(di, a1, b1), 0.f);
        r.z = di * fmaxf(fmaf(di, a2, b2), 0.f);
        r.w = di * fmaxf(fmaf(di, a3, b3), 0.f);
      } else if (EMODE == 2) {
        r.x = fmaxf(fmaf(di, a0, b0), 0.f);
        r.y = fmaxf(fmaf(di, a1, b1), 0.f);
        r.z = fmaxf(fmaf(di, a2, b2), 0.f);
        r.w = fmaxf(fmaf(di, a3, b3), 0.f);
      } else {
        r.x = a0 + b0; r.y = a1 + b1; r.z = a2 + b2; r.w = a3 + b3;
      }
      if (OH) {
        __half2 h01 = __floats2half2_rn(r.x, r.y);
        __half2 h23 = __floats2half2_rn(r.z, r.w);
        uint2 pk;
        pk.x = *(unsigned*)&h01;
        pk.y = *(unsigned*)&h23;
        *(uint2*)((__half*)outv + (size_t)n * M + c0 + 4 * j4) = pk;
      } else {
        *(float4*)((float*)outv + (size_t)n * M + c0 + 4 * j4) = r;
      }
    }
  }
}

// ---------- fused layer-2 GEMM + FC via LDS staging ----------
// Block = 256 thr = 4 waves. Phase 1: WAVE = M-slice (c0 = (t>>6)*24,
// wave-uniform -> W2/b2 s_load), LANE = node (nl = t&63).
// h2 slice -> LDS [64][101] (101 mod 32 = 5 -> <=2-way banks, free).
// Phase 2: wave = m-slice of 8 (m0 = (t>>6)*8), lane = node: Wfc/bfc
// wave-uniform -> s_load; sh2 reads 2-way/free.
__global__ __launch_bounds__(256) void sgemm2fc(
    const float* __restrict__ X, const float* __restrict__ W2,
    const float* __restrict__ b2, const float* __restrict__ Wfc,
    const float* __restrict__ bfc, const float* __restrict__ dinv,
    float* __restrict__ out) {
  __shared__ float sh2[64 * 101];  // 25.9 KB
  const int t = threadIdx.x;
  const int nl = t & 63;          // lane = node
  const int c0 = (t >> 6) * 24;   // wave = slice (wave-uniform!)
  const int nr = blockIdx.x * 64 + nl;
  const bool act = nr < NN;
  const int n = act ? nr : NN - 1;

  float acc[24] = {};
  const float4* __restrict__ xr = (const float4*)(X + (size_t)n * 96);
  #pragma unroll 4
  for (int kq = 0; kq < 24; ++kq) {
    float4 xv = xr[kq];
    const float xk[4] = {xv.x, xv.y, xv.z, xv.w};
    #pragma unroll
    for (int c = 0; c < 4; ++c) {
      const float* __restrict__ wrow = W2 + (size_t)(4 * kq + c) * 96 + c0;
      #pragma unroll
      for (int j = 0; j < 24; ++j)  // wave-uniform -> s_load
        acc[j] = fmaf(xk[c], wrow[j], acc[j]);
    }
  }
  {
    const float di = dinv[n];
    float* sp = sh2 + nl * 101 + c0;
    #pragma unroll
    for (int j = 0; j < 24; ++j)
      sp[j] = fmaxf(fmaf(di, acc[j], b2[c0 + j]), 0.f);
  }
  __syncthreads();

  // phase 2: lane = node, wave = m-slice of 8
  const int m0 = (t >> 6) * 8;
  float o[8] = {};
  const float* __restrict__ hrow = sh2 + nl * 101;
  #pragma unroll 8
  for (int k = 0; k < 96; ++k) {
    const float hk = hrow[k];
    const float* __restrict__ wr = Wfc + (size_t)k * 32 + m0;  // uniform
    #pragma unroll
    for (int j = 0; j < 8; ++j) o[j] = fmaf(hk, wr[j], o[j]);
  }
  if (act) {
    float* op = out + (size_t)nr * 32 + m0;
    float4 r0, r1;
    r0.x = o[0] + bfc[m0 + 0]; r0.y = o[1] + bfc[m0 + 1];
    r0.z = o[2] + bfc[m0 + 2]; r0.w = o[3] + bfc[m0 + 3];
    r1.x = o[4] + bfc[m0 + 4]; r1.y = o[5] + bfc[m0 + 5];
    r1.z = o[6] + bfc[m0 + 6]; r1.w = o[7] + bfc[m0 + 7];
    *(float4*)op = r0;
    *(float4*)(op + 4) = r1;
  }
}

extern "C" void kernel_launch(void* const* d_in, const int* in_sizes, int n_in,
                              void* d_out, int out_size, void* d_ws,
                              size_t ws_size, hipStream_t stream) {
  const float* x   = (const float*)d_in[0];
  const int*   ei  = (const int*)d_in[1];
  const float* W1  = (const float*)d_in[2];
  const float* b1  = (const float*)d_in[3];
  const float* W2  = (const float*)d_in[4];
  const float* b2  = (const float*)d_in[5];
  const float* Wfc = (const float*)d_in[6];
  const float* bfc = (const float*)d_in[7];
  float* out = (float*)d_out;

  // workspace: lifetime-reused regions
  //   R0 [NN*96 f32]: u_h (fp16 s64) | g1_h (fp16 s96)
  //   R1 [NN*96 f32]: bbuf | B1 (f32 s64) | B2 (f32 s96)
  float* dinv = (float*)d_ws;                        // [50048]
  float* R0 = dinv + 50048;                          // [NN*96]
  float* R1 = R0 + (size_t)NN * 96;                  // [NN*96]
  int* row_start = (int*)(R1 + (size_t)NN * 96);     // [50048]
  int* counts = row_start + 50048;                   // [50048]
  int* bcnt = counts + 50048;                        // [512]
  unsigned short* srcs = (unsigned short*)(bcnt + 512);  // [NE] u16
  unsigned* perm = (unsigned*)(srcs + NE);           // [NB*NPB]
  unsigned* bbuf = (unsigned*)R1;                    // 4MB scratch
  __half* u_h = (__half*)R0;
  __half* g1_h = (__half*)R0;
  float* B1 = R1;
  float* B2 = R1;

  zero_bcnt<<<1, 512, 0, stream>>>(bcnt);
  csr_pass1<<<NP1, P1B, 0, stream>>>(ei, bcnt, bbuf);
  csr_pass2<<<NB, 256, 0, stream>>>(bcnt, bbuf, x, row_start, counts, dinv,
                                    u_h, srcs, perm);

  constexpr int CH = (NN + 255) / 256;  // 196 node chunks

  // B1 = gather64(u_h, perm): R0 -> R1
  gather_h<64><<<(NB * NPB * 8 + 255) / 256, 256, 0, stream>>>(
      perm, row_start, counts, srcs, u_h, B1);
  // g1_h = fp16(di*relu(di*(B1@W1) + b1)): R1 -> R0  (MS=32, R10-proven)
  sgemm<64, 96, 32, 1, 1><<<CH * 3, 256, 0, stream>>>(B1, W1, b1, dinv, g1_h);
  // B2 = gather96(g1_h, perm): R0 -> R1
  gather_h<96><<<(NB * NPB * 12 + 255) / 256, 256, 0, stream>>>(
      perm, row_start, counts, srcs, g1_h, B2);
  // out = relu(di*(B2@W2)+b2) @ Wfc + bfc: fused, LDS-staged, wave=slice
  sgemm2fc<<<(NN + 63) / 64, 256, 0, stream>>>(B2, W2, b2, Wfc, bfc, dinv,
                                               out);
}

// Round 16
// 128.187 us; speedup vs baseline: 1.5963x; 1.5881x over previous
//
#include <hip/hip_runtime.h>
#include <hip/hip_fp16.h>

// GCN: N=50000 nodes, E=800000 edges, 64 -> 96 -> 96 -> 32, fp32.
// R16: fix sgemm2fc for real. R14==R15 timing (106 vs 104us, same VGPR=40)
// proved the mapping change caused NO codegen change: LLVM divergence
// analysis treats threadIdx.x-derived values (t>>6) as DIVERGENT even though
// they're wave-uniform -> W2 reads were per-lane VMEM in both. Fix:
// __builtin_amdgcn_readfirstlane forces c0/m0 into SGPRs -> W2/Wfc/b2/bfc
// addresses scalar -> s_load, same as the proven split sgemm (whose c0 comes
// from blockIdx, provably uniform).
// Pipeline:
//   pass1: bucket edges by dst/98; pass2: CSR + dinv + perm + u_h=fp16(di*x)
//   B1 = gather64(u_h,perm);  g1_h = fp16(di*relu(di*(B1@W1)+b1))
//   B2 = gather96(g1_h,perm); out = relu(di*(B2@W2)+b2) @ Wfc + bfc [fused]

constexpr int NN = 50000;
constexpr int NE = 800000;
constexpr int NB = 512;     // buckets
constexpr int NPB = 98;     // nodes per bucket (512*98 = 50176 >= NN)
constexpr int BCAP = 2048;  // max edges per bucket (mean 1563; verified fit)
constexpr int EPB = 4096;   // edges per pass1 block
constexpr int P1B = 256;    // pass1 block size
constexpr int NP1 = (NE + EPB - 1) / EPB;  // 196 blocks

__global__ void zero_bcnt(int* bcnt) {
  int i = threadIdx.x;
  if (i < NB) bcnt[i] = 0;
}

// ---------------- CSR pass 1: block-local sort + bulk reservation ----------
__global__ __launch_bounds__(P1B) void csr_pass1(const int* __restrict__ ei,
                                                 int* __restrict__ bcnt,
                                                 unsigned* __restrict__ bbuf) {
  __shared__ unsigned sorted[EPB];  // 16KB
  __shared__ int hist[NB];
  __shared__ int lofs[NB];   // local exclusive prefix
  __shared__ int cursor[NB];
  __shared__ int gbase[NB];  // global reserved base within bucket
  __shared__ int psum[P1B];
  const int t = threadIdx.x;
  const int e0 = blockIdx.x * EPB;
  const int ecnt = min(EPB, NE - e0);

  for (int i = t; i < NB; i += P1B) hist[i] = 0;
  __syncthreads();

  // phase A: histogram (16 edges/thread)
  for (int i = t; i < ecnt; i += P1B) {
    unsigned dst = (unsigned)ei[NE + e0 + i];
    atomicAdd(&hist[dst / NPB], 1);
  }
  __syncthreads();

  // phase B: pair-scan 512 buckets with 256 threads + bulk reservation
  const int h0 = hist[2 * t], h1 = hist[2 * t + 1];
  psum[t] = h0 + h1;
  __syncthreads();
  for (int off = 1; off < P1B; off <<= 1) {
    int v = 0;
    if (t >= off) v = psum[t - off];
    __syncthreads();
    psum[t] += v;
    __syncthreads();
  }
  {
    const int pex = psum[t] - (h0 + h1);  // exclusive pair base
    lofs[2 * t] = pex;
    lofs[2 * t + 1] = pex + h0;
    cursor[2 * t] = pex;
    cursor[2 * t + 1] = pex + h0;
    gbase[2 * t] = atomicAdd(&bcnt[2 * t], h0);
    gbase[2 * t + 1] = atomicAdd(&bcnt[2 * t + 1], h1);
  }
  __syncthreads();

  // phase C: LDS scatter sorted by bucket
  for (int i = t; i < ecnt; i += P1B) {
    unsigned src = (unsigned)ei[e0 + i];
    unsigned dst = (unsigned)ei[NE + e0 + i];
    unsigned b = dst / NPB;
    unsigned dl = dst - b * NPB;
    int pos = atomicAdd(&cursor[b], 1);
    sorted[pos] = (b << 23) | (dl << 16) | src;
  }
  __syncthreads();

  // phase D: run-coalesced global writes
  for (int i = t; i < ecnt; i += P1B) {
    unsigned pw = sorted[i];
    unsigned b = pw >> 23;
    int off_in_b = gbase[b] + (i - lofs[b]);
    if (off_in_b < BCAP)
      bbuf[b * BCAP + off_in_b] = pw & 0x007FFFFFu;  // (dl<<16)|src
  }
}

// ------- CSR pass 2: per-bucket LDS sort + CSR + degree-sorted perm -------
__global__ __launch_bounds__(256) void csr_pass2(
    const int* __restrict__ bcnt, const unsigned* __restrict__ bbuf,
    const float* __restrict__ x, int* __restrict__ row_start,
    int* __restrict__ counts, float* __restrict__ dinv,
    __half* __restrict__ u, unsigned short* __restrict__ srcs,
    unsigned* __restrict__ perm) {
  __shared__ int s_red[256];
  __shared__ int s_cnt[128];
  __shared__ int s_scan[128];
  __shared__ int s_cur[128];
  __shared__ float s_dinv[128];
  __shared__ unsigned short s_sorted[BCAP];
  __shared__ int d_hist[64];
  __shared__ int d_cur[64];
  __shared__ int s_permL[NPB];
  const int b = blockIdx.x, t = threadIdx.x;
  const int cnt_b = min(bcnt[b], BCAP);

  int acc = 0;
  for (int j = t; j < b; j += 256) acc += min(bcnt[j], BCAP);
  s_red[t] = acc;
  __syncthreads();
  for (int off = 128; off > 0; off >>= 1) {
    if (t < off) s_red[t] += s_red[t + off];
    __syncthreads();
  }
  const int base = s_red[0];

  if (t < 128) s_cnt[t] = 0;
  __syncthreads();
  for (int i = t; i < cnt_b; i += 256)
    atomicAdd(&s_cnt[bbuf[b * BCAP + i] >> 16], 1);
  __syncthreads();

  if (t < 128) s_scan[t] = s_cnt[t];
  __syncthreads();
  for (int off = 1; off < 128; off <<= 1) {
    int v = 0;
    if (t < 128 && t >= off) v = s_scan[t - off];
    __syncthreads();
    if (t < 128) s_scan[t] += v;
    __syncthreads();
  }
  if (t < 128) s_cur[t] = s_scan[t] - s_cnt[t];  // exclusive

  const int node = b * NPB + t;
  if (t < NPB && node < NN) {
    int c = s_cnt[t];
    row_start[node] = base + s_scan[t] - c;
    counts[node] = c;
    float di = rsqrtf(1.0f + (float)c);
    dinv[node] = di;
    s_dinv[t] = di;
  }
  __syncthreads();

  for (int i = t; i < cnt_b; i += 256) {
    unsigned w = bbuf[b * BCAP + i];
    int pos = atomicAdd(&s_cur[w >> 16], 1);
    s_sorted[pos] = (unsigned short)(w & 0xFFFFu);
  }
  __syncthreads();
  for (int i = t; i < cnt_b; i += 256) srcs[base + i] = s_sorted[i];

  // ---- degree-sorted perm for this bucket (s_cnt intact) ----
  const int na = max(0, min(NN - b * NPB, NPB));  // active nodes in bucket
  if (t < 64) d_hist[t] = 0;
  __syncthreads();
  const bool activeN = (t < na);
  const int deg = activeN ? min(s_cnt[t], 63) : 0;
  if (activeN) atomicAdd(&d_hist[deg], 1);
  __syncthreads();
  if (t < 64) d_cur[t] = d_hist[t];
  __syncthreads();
  for (int off = 1; off < 64; off <<= 1) {
    int v = 0;
    if (t < 64 && t >= off) v = d_cur[t - off];
    __syncthreads();
    if (t < 64) d_cur[t] += v;
    __syncthreads();
  }
  if (t < 64) d_cur[t] -= d_hist[t];  // exclusive
  __syncthreads();
  if (activeN) {
    int r = atomicAdd(&d_cur[deg], 1);
    s_permL[r] = t;
  }
  __syncthreads();
  if (t < NPB)
    perm[b * NPB + t] =
        (t < na) ? (unsigned)(b * NPB + s_permL[t]) : 0xFFFFFFFFu;

  // fused: u = fp16(dinv * x), stride 64 halves
  const float4* x4 = (const float4*)x;
  for (int i = t; i < NPB * 16; i += 256) {
    int nl = i >> 4, q = i & 15;
    int n = b * NPB + nl;
    if (n < NN) {
      float di = s_dinv[nl];
      float4 v = x4[(size_t)n * 16 + q];
      __half2 h01 = __floats2half2_rn(v.x * di, v.y * di);
      __half2 h23 = __floats2half2_rn(v.z * di, v.w * di);
      uint2 pk;
      pk.x = *(unsigned*)&h01;
      pk.y = *(unsigned*)&h23;
      *(uint2*)(u + (size_t)n * 64 + 4 * q) = pk;
    }
  }
}

// ------- perm-ordered gather: B[n] = A[n] + sum_{s in adj(n)} A[s] -------
// A fp16 full rows (16B/lane contiguous, line-friendly); B fp32 sequential.
// Degree-sorted perm order -> uniform loop length per wave. 4-deep MLP.
template <int C>
__global__ __launch_bounds__(256) void gather_h(
    const unsigned* __restrict__ perm, const int* __restrict__ row_start,
    const int* __restrict__ counts, const unsigned short* __restrict__ srcs,
    const __half* __restrict__ A, float* __restrict__ B) {
  constexpr int QP = C / 8;  // 16B chunks per row: 12 (96ch) or 8 (64ch)
  int gid = blockIdx.x * blockDim.x + threadIdx.x;
  if (gid >= NB * NPB * QP) return;
  int i, q;
  if constexpr ((QP & (QP - 1)) == 0) {
    i = gid >> 3;  // QP == 8
    q = gid & 7;
  } else {
    i = gid / QP;
    q = gid - i * QP;
  }
  const unsigned node = perm[i];
  if (node == 0xFFFFFFFFu) return;
  const int n = (int)node;
  const uint4* A4 = (const uint4*)A + q;  // row = QP uint4 (8 halves each)

  float a[8] = {};
  {  // self-loop term
    uint4 v = A4[(size_t)n * QP];
    const __half2* h = (const __half2*)&v;
    #pragma unroll
    for (int k = 0; k < 4; ++k) {
      float2 f = __half22float2(h[k]);
      a[2 * k] = f.x;
      a[2 * k + 1] = f.y;
    }
  }
  const int s0 = row_start[n];
  const int cnt = counts[n];
  int p = 0;
  for (; p + 4 <= cnt; p += 4) {  // 4 independent loads in flight
    int sa = srcs[s0 + p + 0];
    int sb = srcs[s0 + p + 1];
    int sc = srcs[s0 + p + 2];
    int sd = srcs[s0 + p + 3];
    uint4 va = A4[(size_t)sa * QP];
    uint4 vb = A4[(size_t)sb * QP];
    uint4 vc = A4[(size_t)sc * QP];
    uint4 vd = A4[(size_t)sd * QP];
    const __half2* ha = (const __half2*)&va;
    const __half2* hb = (const __half2*)&vb;
    const __half2* hc = (const __half2*)&vc;
    const __half2* hd = (const __half2*)&vd;
    #pragma unroll
    for (int k = 0; k < 4; ++k) {
      float2 fa = __half22float2(ha[k]);
      float2 fb = __half22float2(hb[k]);
      float2 fc = __half22float2(hc[k]);
      float2 fd = __half22float2(hd[k]);
      a[2 * k] += (fa.x + fb.x) + (fc.x + fd.x);
      a[2 * k + 1] += (fa.y + fb.y) + (fc.y + fd.y);
    }
  }
  for (; p < cnt; ++p) {
    int s = srcs[s0 + p];
    uint4 v = A4[(size_t)s * QP];
    const __half2* h = (const __half2*)&v;
    #pragma unroll
    for (int k = 0; k < 4; ++k) {
      float2 f = __half22float2(h[k]);
      a[2 * k] += f.x;
      a[2 * k + 1] += f.y;
    }
  }
  float* bp = B + (size_t)n * C + 8 * q;
  *(float4*)bp = make_float4(a[0], a[1], a[2], a[3]);
  *(float4*)(bp + 4) = make_float4(a[4], a[5], a[6], a[7]);
}

// ---------------- SGPR-W row GEMM (layer 1) ----------------
// thread = (node, M-slice of MS). acc in VGPRs; W via wave-uniform s_load.
// EMODE 1: di*relu(di*acc+b).  OH: fp16 out.
template <int K, int M, int MS, int EMODE, int OH>
__global__ __launch_bounds__(256) void sgemm(
    const float* __restrict__ X, const float* __restrict__ W,
    const float* __restrict__ bias, const float* __restrict__ dinv,
    void* __restrict__ outv) {
  constexpr int NS = M / MS;
  constexpr int WQ = MS / 4;
  const int bid = blockIdx.x;
  const int chunk = (NS == 1) ? bid : bid / NS;
  const int slice = (NS == 1) ? 0 : bid - chunk * NS;
  const int c0 = slice * MS;
  const int t = threadIdx.x;
  const int nr = chunk * 256 + t;
  const bool act = nr < NN;
  const int n = act ? nr : NN - 1;  // clamp: safe loads, store guarded

  float acc[MS] = {};
  const float4* __restrict__ xr = (const float4*)(X + (size_t)n * K);
  #pragma unroll 4
  for (int kq = 0; kq < K / 4; ++kq) {
    float4 xv = xr[kq];
    const float xk[4] = {xv.x, xv.y, xv.z, xv.w};
    #pragma unroll
    for (int c = 0; c < 4; ++c) {
      const float* __restrict__ wrow = W + (size_t)(4 * kq + c) * M + c0;
      #pragma unroll
      for (int j = 0; j < MS; ++j)  // wrow[j] is wave-uniform -> s_load
        acc[j] = fmaf(xk[c], wrow[j], acc[j]);
    }
  }

  if (act) {
    const float di = (EMODE != 3) ? dinv[n] : 0.f;
    #pragma unroll
    for (int j4 = 0; j4 < WQ; ++j4) {
      float b0 = bias[c0 + 4 * j4 + 0], b1 = bias[c0 + 4 * j4 + 1];
      float b2 = bias[c0 + 4 * j4 + 2], b3 = bias[c0 + 4 * j4 + 3];
      float a0 = acc[4 * j4 + 0], a1 = acc[4 * j4 + 1];
      float a2 = acc[4 * j4 + 2], a3 = acc[4 * j4 + 3];
      float4 r;
      if (EMODE == 1) {
        r.x = di * fmaxf(fmaf(di, a0, b0), 0.f);
        r.y = di * fmaxf(fmaf(di, a1, b1), 0.f);
        r.z = di * fmaxf(fmaf(di, a2, b2), 0.f);
        r.w = di * fmaxf(fmaf(di, a3, b3), 0.f);
      } else if (EMODE == 2) {
        r.x = fmaxf(fmaf(di, a0, b0), 0.f);
        r.y = fmaxf(fmaf(di, a1, b1), 0.f);
        r.z = fmaxf(fmaf(di, a2, b2), 0.f);
        r.w = fmaxf(fmaf(di, a3, b3), 0.f);
      } else {
        r.x = a0 + b0; r.y = a1 + b1; r.z = a2 + b2; r.w = a3 + b3;
      }
      if (OH) {
        __half2 h01 = __floats2half2_rn(r.x, r.y);
        __half2 h23 = __floats2half2_rn(r.z, r.w);
        uint2 pk;
        pk.x = *(unsigned*)&h01;
        pk.y = *(unsigned*)&h23;
        *(uint2*)((__half*)outv + (size_t)n * M + c0 + 4 * j4) = pk;
      } else {
        *(float4*)((float*)outv + (size_t)n * M + c0 + 4 * j4) = r;
      }
    }
  }
}

// ---------- fused layer-2 GEMM + FC via LDS staging ----------
// Block = 256 thr = 4 waves; wave = M-slice, lane = node. The slice index
// (t>>6) is wave-uniform but LLVM divergence analysis can't prove it ->
// readfirstlane forces it into an SGPR so W2/Wfc/b2/bfc reads are s_load.
__global__ __launch_bounds__(256) void sgemm2fc(
    const float* __restrict__ X, const float* __restrict__ W2,
    const float* __restrict__ b2, const float* __restrict__ Wfc,
    const float* __restrict__ bfc, const float* __restrict__ dinv,
    float* __restrict__ out) {
  __shared__ float sh2[64 * 101];  // 25.9 KB
  const int t = threadIdx.x;
  const int nl = t & 63;  // lane = node
  const int c0 = __builtin_amdgcn_readfirstlane((t >> 6) * 24);  // SGPR
  const int nr = blockIdx.x * 64 + nl;
  const bool act = nr < NN;
  const int n = act ? nr : NN - 1;

  float acc[24] = {};
  const float4* __restrict__ xr = (const float4*)(X + (size_t)n * 96);
  #pragma unroll 4
  for (int kq = 0; kq < 24; ++kq) {
    float4 xv = xr[kq];
    const float xk[4] = {xv.x, xv.y, xv.z, xv.w};
    #pragma unroll
    for (int c = 0; c < 4; ++c) {
      const float* __restrict__ wrow = W2 + (size_t)(4 * kq + c) * 96 + c0;
      #pragma unroll
      for (int j = 0; j < 24; ++j)  // scalar address -> s_load
        acc[j] = fmaf(xk[c], wrow[j], acc[j]);
    }
  }
  {
    const float di = dinv[n];
    float* sp = sh2 + nl * 101 + c0;
    #pragma unroll
    for (int j = 0; j < 24; ++j)
      sp[j] = fmaxf(fmaf(di, acc[j], b2[c0 + j]), 0.f);
  }
  __syncthreads();

  // phase 2: lane = node, wave = m-slice of 8 (SGPR via readfirstlane)
  const int m0 = __builtin_amdgcn_readfirstlane((t >> 6) * 8);
  float o[8] = {};
  const float* __restrict__ hrow = sh2 + nl * 101;
  #pragma unroll 8
  for (int k = 0; k < 96; ++k) {
    const float hk = hrow[k];
    const float* __restrict__ wr = Wfc + (size_t)k * 32 + m0;  // scalar
    #pragma unroll
    for (int j = 0; j < 8; ++j) o[j] = fmaf(hk, wr[j], o[j]);
  }
  if (act) {
    float* op = out + (size_t)nr * 32 + m0;
    float4 r0, r1;
    r0.x = o[0] + bfc[m0 + 0]; r0.y = o[1] + bfc[m0 + 1];
    r0.z = o[2] + bfc[m0 + 2]; r0.w = o[3] + bfc[m0 + 3];
    r1.x = o[4] + bfc[m0 + 4]; r1.y = o[5] + bfc[m0 + 5];
    r1.z = o[6] + bfc[m0 + 6]; r1.w = o[7] + bfc[m0 + 7];
    *(float4*)op = r0;
    *(float4*)(op + 4) = r1;
  }
}

extern "C" void kernel_launch(void* const* d_in, const int* in_sizes, int n_in,
                              void* d_out, int out_size, void* d_ws,
                              size_t ws_size, hipStream_t stream) {
  const float* x   = (const float*)d_in[0];
  const int*   ei  = (const int*)d_in[1];
  const float* W1  = (const float*)d_in[2];
  const float* b1  = (const float*)d_in[3];
  const float* W2  = (const float*)d_in[4];
  const float* b2  = (const float*)d_in[5];
  const float* Wfc = (const float*)d_in[6];
  const float* bfc = (const float*)d_in[7];
  float* out = (float*)d_out;

  // workspace: lifetime-reused regions
  //   R0 [NN*96 f32]: u_h (fp16 s64) | g1_h (fp16 s96)
  //   R1 [NN*96 f32]: bbuf | B1 (f32 s64) | B2 (f32 s96)
  float* dinv = (float*)d_ws;                        // [50048]
  float* R0 = dinv + 50048;                          // [NN*96]
  float* R1 = R0 + (size_t)NN * 96;                  // [NN*96]
  int* row_start = (int*)(R1 + (size_t)NN * 96);     // [50048]
  int* counts = row_start + 50048;                   // [50048]
  int* bcnt = counts + 50048;                        // [512]
  unsigned short* srcs = (unsigned short*)(bcnt + 512);  // [NE] u16
  unsigned* perm = (unsigned*)(srcs + NE);           // [NB*NPB]
  unsigned* bbuf = (unsigned*)R1;                    // 4MB scratch
  __half* u_h = (__half*)R0;
  __half* g1_h = (__half*)R0;
  float* B1 = R1;
  float* B2 = R1;

  zero_bcnt<<<1, 512, 0, stream>>>(bcnt);
  csr_pass1<<<NP1, P1B, 0, stream>>>(ei, bcnt, bbuf);
  csr_pass2<<<NB, 256, 0, stream>>>(bcnt, bbuf, x, row_start, counts, dinv,
                                    u_h, srcs, perm);

  constexpr int CH = (NN + 255) / 256;  // 196 node chunks

  // B1 = gather64(u_h, perm): R0 -> R1
  gather_h<64><<<(NB * NPB * 8 + 255) / 256, 256, 0, stream>>>(
      perm, row_start, counts, srcs, u_h, B1);
  // g1_h = fp16(di*relu(di*(B1@W1) + b1)): R1 -> R0  (MS=32, R10-proven)
  sgemm<64, 96, 32, 1, 1><<<CH * 3, 256, 0, stream>>>(B1, W1, b1, dinv, g1_h);
  // B2 = gather96(g1_h, perm): R0 -> R1
  gather_h<96><<<(NB * NPB * 12 + 255) / 256, 256, 0, stream>>>(
      perm, row_start, counts, srcs, g1_h, B2);
  // out = relu(di*(B2@W2)+b2) @ Wfc + bfc: fused, readfirstlane-scalarized
  sgemm2fc<<<(NN + 63) / 64, 256, 0, stream>>>(B2, W2, b2, Wfc, bfc, dinv,
                                               out);
}